// Round 1
// baseline (4229.339 us; speedup 1.0000x reference)
//
#include <hip/hip_runtime.h>

typedef __attribute__((ext_vector_type(8))) short bf16x8;
typedef __attribute__((ext_vector_type(4))) float f32x4;
typedef __attribute__((ext_vector_type(4))) unsigned int u32x4;

#define AG  __HIP_MEMORY_SCOPE_AGENT
#define RLX __ATOMIC_RELAXED

__device__ __forceinline__ unsigned short f2b(float x){
  union { float f; unsigned u; } v; v.f = x;
  unsigned r = v.u + 0x7FFFu + ((v.u >> 16) & 1u);
  return (unsigned short)(r >> 16);
}
__device__ __forceinline__ float b2f(unsigned short h){
  union { float f; unsigned u; } v; v.u = ((unsigned)h) << 16; return v.f;
}
__device__ __forceinline__ float rcpf_(float x){ return __builtin_amdgcn_rcpf(x); }
__device__ __forceinline__ float tanhf_(float x){
  x = fminf(15.f, fmaxf(-15.f, x));
  float e = __expf(2.f*x);
  return (e - 1.f) * rcpf_(e + 1.f);
}
__device__ __forceinline__ float sigf_(float x){
  x = fminf(30.f, fmaxf(-30.f, x));
  return rcpf_(1.f + __expf(-x));
}

// ---------------- conversion / layout prep (unchanged) ----------------
__global__ void k_convert(const float* __restrict__ h_s, const float* __restrict__ w_a,
                          const float* __restrict__ W_ih, const float* __restrict__ v_a,
                          const float* __restrict__ W_hh, const float* __restrict__ b_ih,
                          const float* __restrict__ b_hh,
                          unsigned short* __restrict__ hs_b, unsigned short* __restrict__ Wcomb,
                          unsigned short* __restrict__ Wv, unsigned short* __restrict__ Whh_p,
                          float* __restrict__ bias_p)
{
  const int total = 4194304 + 524288 + 2097152 + 262144 + 1048576 + 2048;
  for (int i = blockIdx.x*256 + threadIdx.x; i < total; i += gridDim.x*256) {
    int j = i;
    if (j < 4194304) { hs_b[j] = f2b(h_s[j]); continue; }
    j -= 4194304;
    if (j < 524288) { int k = j >> 9, n = j & 511;
      Wcomb[n*1024 + k] = f2b(w_a[k*512 + n]); continue; }
    j -= 524288;
    if (j < 2097152) { int rp = j >> 10, k = j & 1023;
      int h = rp >> 2, g = rp & 3;
      Wcomb[(512 + rp)*1024 + k] = f2b(W_ih[(g*512 + h)*1024 + k]); continue; }
    j -= 2097152;
    if (j < 262144) { int k = j >> 9, h = j & 511;
      Wv[h*512 + k] = f2b(v_a[k*512 + h]); continue; }
    j -= 262144;
    if (j < 1048576) { int rp = j >> 9, k = j & 511;
      int h = rp >> 2, g = rp & 3;
      Whh_p[rp*512 + k] = f2b(W_hh[(g*512 + h)*512 + k]); continue; }
    j -= 1048576;
    { int rp = j; int h = rp >> 2, g = rp & 3;
      bias_p[rp] = b_ih[g*512 + h] + b_hh[g*512 + h]; }
  }
}

// transpose [1536][32000] fp32 (w_b stacked on v_b) -> Bt [32000][1536] bf16
__global__ __launch_bounds__(256) void k_convB(const float* __restrict__ w_b,
                                               const float* __restrict__ v_b,
                                               unsigned short* __restrict__ Bt)
{
  __shared__ unsigned short T[64*80];
  const int k0 = blockIdx.x*64, n0 = blockIdx.y*64;
  const int tx = threadIdx.x;
  const int kk = tx >> 4, nn = (tx & 15)*4;
  #pragma unroll
  for (int i = 0; i < 4; ++i) {
    int kr = k0 + kk + i*16;
    const float* src = (kr < 512) ? &w_b[(size_t)kr*32000 + n0 + nn]
                                  : &v_b[(size_t)(kr-512)*32000 + n0 + nn];
    f32x4 v = *(const f32x4*)src;
    T[(nn+0)*80 + kk + i*16] = f2b(v.x);
    T[(nn+1)*80 + kk + i*16] = f2b(v.y);
    T[(nn+2)*80 + kk + i*16] = f2b(v.z);
    T[(nn+3)*80 + kk + i*16] = f2b(v.w);
  }
  __syncthreads();
  #pragma unroll
  for (int i = 0; i < 2; ++i) {
    int p = tx + i*256;
    int nrow = p >> 3, kp = p & 7;
    *(u32x4*)&Bt[(size_t)(n0+nrow)*1536 + k0 + kp*8] = *(const u32x4*)&T[nrow*80 + kp*8];
  }
}

// ---------------- generic bf16 MFMA GEMM (unchanged) ----------------
#define BM 128
#define BN 128
#define BK 64
#define LDT 72

__global__ __launch_bounds__(256) void k_gemm(
  const unsigned short* __restrict__ A,
  const float* __restrict__ B0, const float* __restrict__ B1, int bsplit,
  const unsigned short* __restrict__ Bnk, int mode,
  void* __restrict__ C0, void* __restrict__ C1, int ncut, int ldc0, int ldc1, int cbf,
  float* __restrict__ Zp,
  int M, int N, int K)
{
  __shared__ unsigned short As[BM*LDT];
  __shared__ unsigned short Bs[BN*LDT];
  const int tx = threadIdx.x;
  const int m0 = blockIdx.x * BM, n0 = blockIdx.y * BN;
  const int wave = tx >> 6, lane = tx & 63;
  const int wm = (wave >> 1) * 64, wn = (wave & 1) * 64;
  const int q = lane >> 4, r16 = lane & 15;
  f32x4 acc[4][4];
  #pragma unroll
  for (int i=0;i<4;i++)
    #pragma unroll
    for (int j=0;j<4;j++) acc[i][j] = (f32x4){0.f,0.f,0.f,0.f};

  for (int k0 = 0; k0 < K; k0 += BK) {
    #pragma unroll
    for (int i = 0; i < 4; ++i) {
      int idx = tx + i*256;
      int row = idx >> 3, piece = idx & 7;
      *(u32x4*)&As[row*LDT + piece*8] =
        *(const u32x4*)&A[(size_t)(m0+row)*K + k0 + piece*8];
    }
    if (mode == 0) {
      #pragma unroll
      for (int i = 0; i < 8; ++i) {
        int idx = tx + i*256;
        int kk = idx >> 5, nn = (idx & 31)*4;
        int kg = k0 + kk;
        const float* src = (kg < bsplit) ? (B0 + (size_t)kg*N) : (B1 + (size_t)(kg - bsplit)*N);
        f32x4 v = *(const f32x4*)&src[n0 + nn];
        Bs[(nn+0)*LDT + kk] = f2b(v.x);
        Bs[(nn+1)*LDT + kk] = f2b(v.y);
        Bs[(nn+2)*LDT + kk] = f2b(v.z);
        Bs[(nn+3)*LDT + kk] = f2b(v.w);
      }
    } else {
      #pragma unroll
      for (int i = 0; i < 4; ++i) {
        int idx = tx + i*256;
        int row = idx >> 3, piece = idx & 7;
        *(u32x4*)&Bs[row*LDT + piece*8] =
          *(const u32x4*)&Bnk[(size_t)(n0+row)*K + k0 + piece*8];
      }
    }
    __syncthreads();
    #pragma unroll
    for (int kk = 0; kk < BK; kk += 32) {
      bf16x8 af[4], bfv[4];
      #pragma unroll
      for (int i=0;i<4;i++) af[i] = *(const bf16x8*)&As[(wm + i*16 + r16)*LDT + kk + q*8];
      #pragma unroll
      for (int j=0;j<4;j++) bfv[j] = *(const bf16x8*)&Bs[(wn + j*16 + r16)*LDT + kk + q*8];
      #pragma unroll
      for (int i=0;i<4;i++)
        #pragma unroll
        for (int j=0;j<4;j++)
          acc[i][j] = __builtin_amdgcn_mfma_f32_16x16x32_bf16(af[i], bfv[j], acc[i][j], 0,0,0);
    }
    __syncthreads();
  }
  if (Zp) {
    #pragma unroll
    for (int i=0;i<4;i++)
      #pragma unroll
      for (int reg=0; reg<4; ++reg) {
        float z = __expf(acc[i][0][reg]) + __expf(acc[i][1][reg])
                + __expf(acc[i][2][reg]) + __expf(acc[i][3][reg]);
        z += __shfl_xor(z, 1, 64); z += __shfl_xor(z, 2, 64);
        z += __shfl_xor(z, 4, 64); z += __shfl_xor(z, 8, 64);
        if (r16 == 0) atomicAdd(&Zp[m0 + wm + i*16 + q*4 + reg], z);
      }
  }
  #pragma unroll
  for (int i=0;i<4;i++)
    #pragma unroll
    for (int j=0;j<4;j++) {
      int n = n0 + wn + j*16 + r16;
      #pragma unroll
      for (int reg=0; reg<4; ++reg) {
        int m = m0 + wm + i*16 + q*4 + reg;
        float v = acc[i][j][reg];
        if (n < ncut) {
          if (cbf) ((unsigned short*)C0)[(size_t)m*ldc0 + n] = f2b(v);
          else     ((float*)C0)[(size_t)m*ldc0 + n] = v;
        } else {
          if (cbf) ((unsigned short*)C1)[(size_t)m*ldc1 + (n-ncut)] = f2b(v);
          else     ((float*)C1)[(size_t)m*ldc1 + (n-ncut)] = v;
        }
      }
    }
}

// ---------------- per-batch group barrier: relaxed agent atomics ONLY ----------------
// No acq/rel, no fences => no buffer_inv/buffer_wbl2 => XCD L2 never invalidated.
// Visibility contract: all cross-WG data moves via relaxed AGENT atomics (MALL-coherent,
// L1/L2-bypassing); __syncthreads drains vmcnt(0) per wave BEFORE the flag store, so a
// WG's comm stores are globally visible before its arrival flag is observable.
// Flags are monotonic phase counters -> no reset, no reuse races.
__device__ __forceinline__ void group_bar(unsigned* slots, int ch, int wv, int lane,
                                          unsigned ph, volatile int* dead)
{
  __syncthreads();                 // drains this WG's comm stores (vmcnt 0) + orders LDS
  if (wv == 0 && !*dead) {
    if (lane == 0)
      __hip_atomic_store(&slots[ch], ph, RLX, AG);
    long sp = 0;
    for (;;) {
      unsigned v = __hip_atomic_load(&slots[lane & 7], RLX, AG);
      if (__all((int)(v >= ph))) break;
      __builtin_amdgcn_s_sleep(2);
      if (++sp > 1500000L) { *dead = 1; break; }
    }
  }
  __syncthreads();
}

__device__ __forceinline__ float dot8_(bf16x8 w8, const float* sp) {
  float a0 =      b2f((unsigned short)w8[0]) * sp[0];
  float a1 =      b2f((unsigned short)w8[1]) * sp[1];
  a0 = fmaf(b2f((unsigned short)w8[2]), sp[2], a0);
  a1 = fmaf(b2f((unsigned short)w8[3]), sp[3], a1);
  a0 = fmaf(b2f((unsigned short)w8[4]), sp[4], a0);
  a1 = fmaf(b2f((unsigned short)w8[5]), sp[5], a1);
  a0 = fmaf(b2f((unsigned short)w8[6]), sp[6], a0);
  a1 = fmaf(b2f((unsigned short)w8[7]), sp[7], a1);
  return a0 + a1;
}

// ---------------- persistent recurrence kernel: 32 independent groups of 8 WGs ----------------
// WG w: b = w>>3, ch = w&7.  (With round-robin WG->XCD dispatch, w%8==ch => all WGs
// reading the same weight slice [Wv/Whh rows of chunk ch] share one XCD's L2.)
// Per step: P1 sva/whh slices (VALU dots) -> bar -> P2 score slice -> bar ->
//           P3 softmax+gates+LSTM+ct -> bar.
// Cross-WG per step per b: s(512 f32) + sva(512 f32) + scores(128 f32) via MALL.
// whh slice and LSTM cell state c live in LDS (WG-private).
__global__ __launch_bounds__(256) void k_recur(
  const unsigned short* __restrict__ wa_h,   // [4096][512] bf16
  const unsigned short* __restrict__ G,      // [4096][2048] bf16
  const unsigned short* __restrict__ hs_b,   // [4096][1024] bf16
  const unsigned short* __restrict__ Wv,     // [512][512]  bf16 (v_a^T)
  const unsigned short* __restrict__ Whh_p,  // [2048][512] bf16 (gate-permuted)
  const float* __restrict__ bias_p,          // [2048]
  const float* __restrict__ s_mask,          // [128*32]
  const float* __restrict__ u_a,             // [512]
  float* __restrict__ s_comm,                // [32][512]  (MALL comm)
  float* __restrict__ sva_comm,              // [32][512]  (MALL comm)
  float* __restrict__ scores_comm,           // [32][128]  (MALL comm)
  unsigned short* __restrict__ Abf,          // [2048][1536] bf16 out
  unsigned* __restrict__ bar)                // [32][64] u32 flag slots
{
  __shared__ float s_sh[512];
  __shared__ float sva_sh[512];
  __shared__ float whh_sh[256];
  __shared__ float AL[128];
  __shared__ float GL[256];
  __shared__ float RD[2048];
  __shared__ float c_sh[64];
  __shared__ float invs;
  __shared__ int s_dead;

  const int w = blockIdx.x, tx = threadIdx.x;
  const int b = w >> 3, ch = w & 7;
  const int wv = tx >> 6, lane = tx & 63;
  unsigned* slots = bar + b*64;

  if (tx == 0) s_dead = 0;
  if (tx < 64) c_sh[tx] = 0.f;
  // zero this WG's slice of s_comm through the same (bypass) path readers use
  if (tx < 64)
    __hip_atomic_store(&s_comm[b*512 + ch*64 + tx], 0.f, RLX, AG);

  const f32x4 ua0 = *(const f32x4*)&u_a[lane*8];
  const f32x4 ua1 = *(const f32x4*)&u_a[lane*8 + 4];

  group_bar(slots, ch, wv, lane, 1u, &s_dead);   // init barrier (s_comm zeroed)

  for (int t = 0; t < 64; ++t) {
    const unsigned ph0 = 2u + 3u*(unsigned)t;

    // ---- P1: sva cols [ch*64,+64) -> MALL; whh cols [ch*256,+256) -> LDS ----
    for (int i = tx; i < 512; i += 256)
      s_sh[i] = __hip_atomic_load(&s_comm[b*512 + i], RLX, AG);
    __syncthreads();
    {
      const float* sp = &s_sh[lane*8];
      const unsigned short* __restrict__ wvb = Wv + (size_t)(ch*64)*512;
      #pragma unroll 4
      for (int r = wv; r < 64; r += 4) {
        bf16x8 w8 = *(const bf16x8*)&wvb[(size_t)r*512 + lane*8];
        float acc = dot8_(w8, sp);
        #pragma unroll
        for (int o = 32; o > 0; o >>= 1) acc += __shfl_down(acc, o, 64);
        if (lane == 0)
          __hip_atomic_store(&sva_comm[b*512 + ch*64 + r], acc, RLX, AG);
      }
      const unsigned short* __restrict__ whb = Whh_p + (size_t)(ch*256)*512;
      #pragma unroll 4
      for (int r = wv; r < 256; r += 4) {
        bf16x8 w8 = *(const bf16x8*)&whb[(size_t)r*512 + lane*8];
        float acc = dot8_(w8, sp);
        #pragma unroll
        for (int o = 32; o > 0; o >>= 1) acc += __shfl_down(acc, o, 64);
        if (lane == 0) whh_sh[r] = acc;
      }
    }
    group_bar(slots, ch, wv, lane, ph0, &s_dead);

    // ---- P2: scores for s in [ch*16,+16), one wave per s ----
    for (int i = tx; i < 512; i += 256)
      sva_sh[i] = __hip_atomic_load(&sva_comm[b*512 + i], RLX, AG);
    __syncthreads();
    {
      const float* sp = &sva_sh[lane*8];
      #pragma unroll
      for (int si = 0; si < 4; ++si) {
        const int s = ch*16 + wv*4 + si;
        bf16x8 w8 = *(const bf16x8*)&wa_h[((size_t)s*32 + b)*512 + lane*8];
        float acc;
        acc  = tanhf_(b2f((unsigned short)w8[0]) + sp[0]) * ua0.x;
        acc += tanhf_(b2f((unsigned short)w8[1]) + sp[1]) * ua0.y;
        acc += tanhf_(b2f((unsigned short)w8[2]) + sp[2]) * ua0.z;
        acc += tanhf_(b2f((unsigned short)w8[3]) + sp[3]) * ua0.w;
        acc += tanhf_(b2f((unsigned short)w8[4]) + sp[4]) * ua1.x;
        acc += tanhf_(b2f((unsigned short)w8[5]) + sp[5]) * ua1.y;
        acc += tanhf_(b2f((unsigned short)w8[6]) + sp[6]) * ua1.z;
        acc += tanhf_(b2f((unsigned short)w8[7]) + sp[7]) * ua1.w;
        #pragma unroll
        for (int o = 32; o > 0; o >>= 1) acc += __shfl_down(acc, o, 64);
        if (lane == 0)
          __hip_atomic_store(&scores_comm[b*128 + s], acc * s_mask[s*32 + b], RLX, AG);
      }
    }
    group_bar(slots, ch, wv, lane, ph0 + 1u, &s_dead);

    // ---- P3: softmax (unnormalized exp + deferred 1/Z), gates+LSTM, ct ----
    if (tx < 128)
      AL[tx] = __expf(__hip_atomic_load(&scores_comm[b*128 + tx], RLX, AG));
    __syncthreads();
    if (tx < 64) {
      float sm = AL[tx] + AL[tx + 64];
      #pragma unroll
      for (int o = 32; o > 0; o >>= 1) sm += __shfl_down(sm, o, 64);
      if (tx == 0) invs = rcpf_(sm);
    }
    __syncthreads();
    // gates partial: sum_s AL[s] * G[s*32+b][n], n = ch*256 + cg*8 .. +8
    {
      const int cg = tx & 31, sg = tx >> 5;
      const int nn = ch*256 + cg*8;
      float a8[8] = {0.f,0.f,0.f,0.f,0.f,0.f,0.f,0.f};
      #pragma unroll
      for (int k = 0; k < 16; ++k) {
        int s = sg*16 + k;
        float av = AL[s];
        bf16x8 g8 = *(const bf16x8*)&G[((size_t)s*32 + b)*2048 + nn];
        a8[0] += av * b2f((unsigned short)g8[0]); a8[1] += av * b2f((unsigned short)g8[1]);
        a8[2] += av * b2f((unsigned short)g8[2]); a8[3] += av * b2f((unsigned short)g8[3]);
        a8[4] += av * b2f((unsigned short)g8[4]); a8[5] += av * b2f((unsigned short)g8[5]);
        a8[6] += av * b2f((unsigned short)g8[6]); a8[7] += av * b2f((unsigned short)g8[7]);
      }
      #pragma unroll
      for (int j = 0; j < 8; ++j) RD[(cg*8 + j)*8 + sg] = a8[j];
    }
    __syncthreads();
    {
      float sum = 0.f;
      #pragma unroll
      for (int k = 0; k < 8; ++k) sum += RD[tx*8 + k];
      GL[tx] = sum * invs + whh_sh[tx] + bias_p[ch*256 + tx];
    }
    __syncthreads();
    if (tx < 64) {
      float iv = GL[tx*4+0], fv = GL[tx*4+1], gv = GL[tx*4+2], ov = GL[tx*4+3];
      float co = c_sh[tx];
      float cn = sigf_(fv)*co + sigf_(iv)*tanhf_(gv);
      float sn = sigf_(ov)*tanhf_(cn);
      c_sh[tx] = cn;
      __hip_atomic_store(&s_comm[b*512 + ch*64 + tx], sn, RLX, AG);
      Abf[((size_t)t*32 + b)*1536 + ch*64 + tx] = f2b(sn);
    }
    // ct partial: sum_s AL[s] * hs[s*32+b][jj], jj = ch*128 + cg2*8 .. +8
    {
      const int cg2 = tx & 15, sg2 = tx >> 4;
      const int jj = ch*128 + cg2*8;
      float c8[8] = {0.f,0.f,0.f,0.f,0.f,0.f,0.f,0.f};
      #pragma unroll
      for (int k = 0; k < 8; ++k) {
        int s = sg2*8 + k;
        float av = AL[s];
        bf16x8 h8 = *(const bf16x8*)&hs_b[((size_t)s*32 + b)*1024 + jj];
        c8[0] += av * b2f((unsigned short)h8[0]); c8[1] += av * b2f((unsigned short)h8[1]);
        c8[2] += av * b2f((unsigned short)h8[2]); c8[3] += av * b2f((unsigned short)h8[3]);
        c8[4] += av * b2f((unsigned short)h8[4]); c8[5] += av * b2f((unsigned short)h8[5]);
        c8[6] += av * b2f((unsigned short)h8[6]); c8[7] += av * b2f((unsigned short)h8[7]);
      }
      __syncthreads();
      #pragma unroll
      for (int j = 0; j < 8; ++j) RD[(cg2*8 + j)*16 + sg2] = c8[j];
    }
    __syncthreads();
    if (tx < 128) {
      float sum = 0.f;
      #pragma unroll
      for (int k = 0; k < 16; ++k) sum += RD[tx*16 + k];
      Abf[((size_t)t*32 + b)*1536 + 512 + ch*128 + tx] = f2b(sum * invs);
    }
    if (t < 63)
      group_bar(slots, ch, wv, lane, ph0 + 2u, &s_dead);
  }
}

// ---------------- loss + softmax normalize (unchanged) ----------------
__global__ __launch_bounds__(64) void k_loss(const float* __restrict__ L, const float* __restrict__ Z,
                                             const int* __restrict__ t_idx, const float* __restrict__ t_mask,
                                             float* __restrict__ out)
{
  const int b = blockIdx.x, t = threadIdx.x;
  const int row = t*32 + b;
  int id = t_idx[t*32 + b];
  float m = t_mask[t*32 + b];
  float l = L[(size_t)row*32000 + id];
  float v = (__logf(Z[row]) - l) * m;
  float vm = v, mm = m;
  for (int o = 32; o > 0; o >>= 1) { vm += __shfl_down(vm, o, 64); mm += __shfl_down(mm, o, 64); }
  if (t == 0) out[b] = vm / mm;
}

__global__ __launch_bounds__(256) void k_s2(float* __restrict__ L, const float* __restrict__ Z)
{
  const int row = blockIdx.x, tx = threadIdx.x;
  float* p = L + (size_t)row*32000;
  float rz = 1.f / Z[row];
  for (int n = tx; n < 32000; n += 256) p[n] = __expf(p[n]) * rz;
}

// ---------------- host ----------------
extern "C" void kernel_launch(void* const* d_in, const int* in_sizes, int n_in,
                              void* d_out, int out_size, void* d_ws, size_t ws_size,
                              hipStream_t stream)
{
  (void)in_sizes; (void)n_in; (void)out_size;
  const float* h_s    = (const float*)d_in[0];
  const float* s_mask = (const float*)d_in[1];
  const float* w_a    = (const float*)d_in[2];
  const float* v_a    = (const float*)d_in[3];
  const float* u_a    = (const float*)d_in[4];
  const float* w_b    = (const float*)d_in[5];
  const float* v_b    = (const float*)d_in[6];
  const float* W_ih   = (const float*)d_in[7];
  const float* W_hh   = (const float*)d_in[8];
  const float* b_ih   = (const float*)d_in[9];
  const float* b_hh   = (const float*)d_in[10];
  const float* t_mask = (const float*)d_in[11];
  const int*   t_idx  = (const int*)d_in[12];
  float* out = (float*)d_out;
  float* logits = out + 32;

  char* w = (char*)d_ws;
  size_t off = 0;
  auto take = [&](size_t bytes) -> void* {
    void* p = w + off; off += (bytes + 255) & ~(size_t)255; return p;
  };
  unsigned* bar          = (unsigned*)take((size_t)32*64*4);      // flag slots
  float* s_comm          = (float*)take((size_t)32*512*4);
  float* sva_comm        = (float*)take((size_t)32*512*4);
  float* scores_comm     = (float*)take((size_t)32*128*4);
  float* Z               = (float*)take((size_t)2048*4);
  float* bias_p          = (float*)take((size_t)2048*4);
  unsigned short* hs_b   = (unsigned short*)take((size_t)4096*1024*2);
  unsigned short* Wcomb  = (unsigned short*)take((size_t)2560*1024*2);
  unsigned short* Wv     = (unsigned short*)take((size_t)512*512*2);
  unsigned short* Whh_p  = (unsigned short*)take((size_t)2048*512*2);
  unsigned short* wa_hb  = (unsigned short*)take((size_t)4096*512*2);
  unsigned short* G      = (unsigned short*)take((size_t)4096*2048*2);
  unsigned short* Abf    = (unsigned short*)take((size_t)2048*1536*2);
  size_t base_need = off;
  bool useBt = (ws_size >= base_need + (size_t)32000*1536*2 + 256);
  unsigned short* Bt = useBt ? (unsigned short*)take((size_t)32000*1536*2) : nullptr;

  hipMemsetAsync(bar, 0, (size_t)32*64*4, stream);
  hipMemsetAsync(Z, 0, 2048*4, stream);
  k_convert<<<4096, 256, 0, stream>>>(h_s, w_a, W_ih, v_a, W_hh, b_ih, b_hh,
                                      hs_b, Wcomb, Wv, Whh_p, bias_p);
  if (useBt)
    k_convB<<<dim3(24, 500), 256, 0, stream>>>(w_b, v_b, Bt);
  // [wa_h | G] = h_s @ [w_a | W_ih^T(perm)] : M=4096, N=2560, K=1024
  k_gemm<<<dim3(32,20), 256, 0, stream>>>(hs_b, nullptr, nullptr, 0, Wcomb, 1,
                                          wa_hb, G, 512, 512, 2048, 1, nullptr,
                                          4096, 2560, 1024);
  k_recur<<<256, 256, 0, stream>>>(wa_hb, G, hs_b, Wv, Whh_p, bias_p, s_mask, u_a,
                                   s_comm, sva_comm, scores_comm, Abf, bar);
  // logits = [s_new|ct] @ [w_b; v_b] : M=2048, N=32000, K=1536 (+fused Z row-sums)
  if (useBt)
    k_gemm<<<dim3(16,250), 256, 0, stream>>>(Abf, nullptr, nullptr, 0, Bt, 1,
                                             logits, logits, 32000, 32000, 32000, 0, Z,
                                             2048, 32000, 1536);
  else
    k_gemm<<<dim3(16,250), 256, 0, stream>>>(Abf, w_b, v_b, 512, nullptr, 0,
                                             logits, logits, 32000, 32000, 32000, 0, Z,
                                             2048, 32000, 1536);
  k_loss<<<32, 64, 0, stream>>>(logits, Z, t_idx, t_mask, out);
  k_s2<<<2048, 256, 0, stream>>>(logits, Z);
}

// Round 2
// 3050.530 us; speedup vs baseline: 1.3864x; 1.3864x over previous
//
#include <hip/hip_runtime.h>

typedef __attribute__((ext_vector_type(8))) short bf16x8;
typedef __attribute__((ext_vector_type(4))) float f32x4;
typedef __attribute__((ext_vector_type(4))) unsigned int u32x4;

#define AG  __HIP_MEMORY_SCOPE_AGENT
#define RLX __ATOMIC_RELAXED

__device__ __forceinline__ unsigned short f2b(float x){
  union { float f; unsigned u; } v; v.f = x;
  unsigned r = v.u + 0x7FFFu + ((v.u >> 16) & 1u);
  return (unsigned short)(r >> 16);
}
__device__ __forceinline__ float b2f(unsigned short h){
  union { float f; unsigned u; } v; v.u = ((unsigned)h) << 16; return v.f;
}
__device__ __forceinline__ float rcpf_(float x){ return __builtin_amdgcn_rcpf(x); }
__device__ __forceinline__ float tanhf_(float x){
  x = fminf(15.f, fmaxf(-15.f, x));
  float e = __expf(2.f*x);
  return (e - 1.f) * rcpf_(e + 1.f);
}
__device__ __forceinline__ float sigf_(float x){
  x = fminf(30.f, fmaxf(-30.f, x));
  return rcpf_(1.f + __expf(-x));
}

// ---------------- conversion / layout prep (unchanged) ----------------
__global__ void k_convert(const float* __restrict__ h_s, const float* __restrict__ w_a,
                          const float* __restrict__ W_ih, const float* __restrict__ v_a,
                          const float* __restrict__ W_hh, const float* __restrict__ b_ih,
                          const float* __restrict__ b_hh,
                          unsigned short* __restrict__ hs_b, unsigned short* __restrict__ Wcomb,
                          unsigned short* __restrict__ Wv, unsigned short* __restrict__ Whh_p,
                          float* __restrict__ bias_p)
{
  const int total = 4194304 + 524288 + 2097152 + 262144 + 1048576 + 2048;
  for (int i = blockIdx.x*256 + threadIdx.x; i < total; i += gridDim.x*256) {
    int j = i;
    if (j < 4194304) { hs_b[j] = f2b(h_s[j]); continue; }
    j -= 4194304;
    if (j < 524288) { int k = j >> 9, n = j & 511;
      Wcomb[n*1024 + k] = f2b(w_a[k*512 + n]); continue; }
    j -= 524288;
    if (j < 2097152) { int rp = j >> 10, k = j & 1023;
      int h = rp >> 2, g = rp & 3;
      Wcomb[(512 + rp)*1024 + k] = f2b(W_ih[(g*512 + h)*1024 + k]); continue; }
    j -= 2097152;
    if (j < 262144) { int k = j >> 9, h = j & 511;
      Wv[h*512 + k] = f2b(v_a[k*512 + h]); continue; }
    j -= 262144;
    if (j < 1048576) { int rp = j >> 9, k = j & 511;
      int h = rp >> 2, g = rp & 3;
      Whh_p[rp*512 + k] = f2b(W_hh[(g*512 + h)*512 + k]); continue; }
    j -= 1048576;
    { int rp = j; int h = rp >> 2, g = rp & 3;
      bias_p[rp] = b_ih[g*512 + h] + b_hh[g*512 + h]; }
  }
}

// transpose [1536][32000] fp32 (w_b stacked on v_b) -> Bt [32000][1536] bf16
__global__ __launch_bounds__(256) void k_convB(const float* __restrict__ w_b,
                                               const float* __restrict__ v_b,
                                               unsigned short* __restrict__ Bt)
{
  __shared__ unsigned short T[64*80];
  const int k0 = blockIdx.x*64, n0 = blockIdx.y*64;
  const int tx = threadIdx.x;
  const int kk = tx >> 4, nn = (tx & 15)*4;
  #pragma unroll
  for (int i = 0; i < 4; ++i) {
    int kr = k0 + kk + i*16;
    const float* src = (kr < 512) ? &w_b[(size_t)kr*32000 + n0 + nn]
                                  : &v_b[(size_t)(kr-512)*32000 + n0 + nn];
    f32x4 v = *(const f32x4*)src;
    T[(nn+0)*80 + kk + i*16] = f2b(v.x);
    T[(nn+1)*80 + kk + i*16] = f2b(v.y);
    T[(nn+2)*80 + kk + i*16] = f2b(v.z);
    T[(nn+3)*80 + kk + i*16] = f2b(v.w);
  }
  __syncthreads();
  #pragma unroll
  for (int i = 0; i < 2; ++i) {
    int p = tx + i*256;
    int nrow = p >> 3, kp = p & 7;
    *(u32x4*)&Bt[(size_t)(n0+nrow)*1536 + k0 + kp*8] = *(const u32x4*)&T[nrow*80 + kp*8];
  }
}

// ---------------- generic bf16 MFMA GEMM (unchanged) ----------------
#define BM 128
#define BN 128
#define BK 64
#define LDT 72

__global__ __launch_bounds__(256) void k_gemm(
  const unsigned short* __restrict__ A,
  const float* __restrict__ B0, const float* __restrict__ B1, int bsplit,
  const unsigned short* __restrict__ Bnk, int mode,
  void* __restrict__ C0, void* __restrict__ C1, int ncut, int ldc0, int ldc1, int cbf,
  float* __restrict__ Zp,
  int M, int N, int K)
{
  __shared__ unsigned short As[BM*LDT];
  __shared__ unsigned short Bs[BN*LDT];
  const int tx = threadIdx.x;
  const int m0 = blockIdx.x * BM, n0 = blockIdx.y * BN;
  const int wave = tx >> 6, lane = tx & 63;
  const int wm = (wave >> 1) * 64, wn = (wave & 1) * 64;
  const int q = lane >> 4, r16 = lane & 15;
  f32x4 acc[4][4];
  #pragma unroll
  for (int i=0;i<4;i++)
    #pragma unroll
    for (int j=0;j<4;j++) acc[i][j] = (f32x4){0.f,0.f,0.f,0.f};

  for (int k0 = 0; k0 < K; k0 += BK) {
    #pragma unroll
    for (int i = 0; i < 4; ++i) {
      int idx = tx + i*256;
      int row = idx >> 3, piece = idx & 7;
      *(u32x4*)&As[row*LDT + piece*8] =
        *(const u32x4*)&A[(size_t)(m0+row)*K + k0 + piece*8];
    }
    if (mode == 0) {
      #pragma unroll
      for (int i = 0; i < 8; ++i) {
        int idx = tx + i*256;
        int kk = idx >> 5, nn = (idx & 31)*4;
        int kg = k0 + kk;
        const float* src = (kg < bsplit) ? (B0 + (size_t)kg*N) : (B1 + (size_t)(kg - bsplit)*N);
        f32x4 v = *(const f32x4*)&src[n0 + nn];
        Bs[(nn+0)*LDT + kk] = f2b(v.x);
        Bs[(nn+1)*LDT + kk] = f2b(v.y);
        Bs[(nn+2)*LDT + kk] = f2b(v.z);
        Bs[(nn+3)*LDT + kk] = f2b(v.w);
      }
    } else {
      #pragma unroll
      for (int i = 0; i < 4; ++i) {
        int idx = tx + i*256;
        int row = idx >> 3, piece = idx & 7;
        *(u32x4*)&Bs[row*LDT + piece*8] =
          *(const u32x4*)&Bnk[(size_t)(n0+row)*K + k0 + piece*8];
      }
    }
    __syncthreads();
    #pragma unroll
    for (int kk = 0; kk < BK; kk += 32) {
      bf16x8 af[4], bfv[4];
      #pragma unroll
      for (int i=0;i<4;i++) af[i] = *(const bf16x8*)&As[(wm + i*16 + r16)*LDT + kk + q*8];
      #pragma unroll
      for (int j=0;j<4;j++) bfv[j] = *(const bf16x8*)&Bs[(wn + j*16 + r16)*LDT + kk + q*8];
      #pragma unroll
      for (int i=0;i<4;i++)
        #pragma unroll
        for (int j=0;j<4;j++)
          acc[i][j] = __builtin_amdgcn_mfma_f32_16x16x32_bf16(af[i], bfv[j], acc[i][j], 0,0,0);
    }
    __syncthreads();
  }
  if (Zp) {
    #pragma unroll
    for (int i=0;i<4;i++)
      #pragma unroll
      for (int reg=0; reg<4; ++reg) {
        float z = __expf(acc[i][0][reg]) + __expf(acc[i][1][reg])
                + __expf(acc[i][2][reg]) + __expf(acc[i][3][reg]);
        z += __shfl_xor(z, 1, 64); z += __shfl_xor(z, 2, 64);
        z += __shfl_xor(z, 4, 64); z += __shfl_xor(z, 8, 64);
        if (r16 == 0) atomicAdd(&Zp[m0 + wm + i*16 + q*4 + reg], z);
      }
  }
  #pragma unroll
  for (int i=0;i<4;i++)
    #pragma unroll
    for (int j=0;j<4;j++) {
      int n = n0 + wn + j*16 + r16;
      #pragma unroll
      for (int reg=0; reg<4; ++reg) {
        int m = m0 + wm + i*16 + q*4 + reg;
        float v = acc[i][j][reg];
        if (n < ncut) {
          if (cbf) ((unsigned short*)C0)[(size_t)m*ldc0 + n] = f2b(v);
          else     ((float*)C0)[(size_t)m*ldc0 + n] = v;
        } else {
          if (cbf) ((unsigned short*)C1)[(size_t)m*ldc1 + (n-ncut)] = f2b(v);
          else     ((float*)C1)[(size_t)m*ldc1 + (n-ncut)] = v;
        }
      }
    }
}

// ---------------- fence-free grid barrier: relaxed agent atomics, monotonic ----------------
// Layout (u32): slots i*32 for i<16 (128B apart), master at [512], gen at [520].
// No acq/rel/fences anywhere -> no buffer_wbl2/buffer_inv -> L2 stays warm.
// Visibility: all cross-WG data uses relaxed AGENT atomics (MALL-coherent); the explicit
// s_waitcnt vmcnt(0) guarantees this WG's comm stores are ACKED at MALL before its
// arrival add is issued; consumer loads issue only after observing gen at MALL.
// (Protocol correctness verified on HW in the round-1 run.)
__device__ __forceinline__ void gbar(unsigned* bar, int w, unsigned ph, volatile int* dead) {
  __syncthreads();
  if (*dead) return;
  if (threadIdx.x == 0) {
    asm volatile("s_waitcnt vmcnt(0)" ::: "memory");
    unsigned* gen = bar + 520;
    unsigned a = __hip_atomic_fetch_add(&bar[(w & 15)*32], 1u, RLX, AG);
    if (a == ph*16u - 1u) {
      unsigned m = __hip_atomic_fetch_add(bar + 512, 1u, RLX, AG);
      if (m == ph*16u - 1u)
        __hip_atomic_store(gen, ph, RLX, AG);
    }
    long sp = 0;
    while (__hip_atomic_load(gen, RLX, AG) < ph) {
      __builtin_amdgcn_s_sleep(4);
      if (++sp > 3000000L) { *dead = 1; break; }
    }
  }
  __syncthreads();
}

// ---------------- persistent recurrence kernel ----------------
// Round-0 decomposition (P1 batched MFMA over 160 WGs; P2 scores over 256 WGs;
// P3 per-(b,ch) softmax/gates/LSTM/ct), with ALL cross-WG traffic through relaxed
// agent atomics and zero fences. s state crosses steps as packed bf16 pairs (s_bf),
// staged coalesced into LDS for P1's MFMA fragments. Cell state c lives in LDS.
__global__ __launch_bounds__(256) void k_recur(
  const unsigned short* __restrict__ wa_h,   // [4096][512] bf16
  const unsigned short* __restrict__ G,      // [4096][2048] bf16
  const unsigned short* __restrict__ hs_b,   // [4096][1024] bf16
  const unsigned short* __restrict__ Wv,     // [512][512]  bf16 (v_a^T)
  const unsigned short* __restrict__ Whh_p,  // [2048][512] bf16 (gate-permuted)
  const float* __restrict__ bias_p,          // [2048]
  const float* __restrict__ s_mask,          // [128*32]
  const float* __restrict__ u_a,             // [512]
  float* __restrict__ sva_g,                 // [32][512]  (MALL comm)
  float* __restrict__ whh_g,                 // [32][2048] (MALL comm)
  float* __restrict__ scores_g,              // [32][128]  (MALL comm)
  unsigned* __restrict__ s_bf,               // [32][256] u32 = packed bf16 pairs (MALL comm)
  unsigned short* __restrict__ Abf,          // [2048][1536] bf16 out (plain, for k_gemm)
  unsigned* bar)
{
  __shared__ unsigned s_lds[32*260];   // staged s as bf16-pairs, padded rows (33.3 KB)
  __shared__ float AL[128];
  __shared__ float GL[256];
  __shared__ float RD[2048];
  __shared__ float c_sh[64];
  __shared__ int s_dead;

  const int w = blockIdx.x, tx = threadIdx.x;
  const int wave = tx >> 6, lane = tx & 63;
  if (tx == 0) s_dead = 0;
  if (tx < 64) c_sh[tx] = 0.f;

  const f32x4 ua0 = *(const f32x4*)&u_a[lane*8];
  const f32x4 ua1 = *(const f32x4*)&u_a[lane*8 + 4];

  for (int t = 0; t < 64; ++t) {
    const unsigned ph0 = 1u + 3u*(unsigned)t;

    // ---- P1 (w<160): stage s (bf16 pairs) -> LDS, then sva|whh cols [w*16,+16) via MFMA ----
    if (w < 160) {
      #pragma unroll 8
      for (int i = tx; i < 32*256; i += 256) {
        unsigned v = __hip_atomic_load(&s_bf[i], RLX, AG);
        s_lds[(i >> 8)*260 + (i & 255)] = v;
      }
      __syncthreads();
      const int q = lane >> 4, rl = lane & 15;
      const int ncol = w*16 + rl;
      const unsigned short* bp = (ncol < 512) ? (Wv + (size_t)ncol*512)
                                              : (Whh_p + (size_t)(ncol-512)*512);
      f32x4 a0 = (f32x4){0.f,0.f,0.f,0.f}, a1 = (f32x4){0.f,0.f,0.f,0.f};
      #pragma unroll
      for (int ks = 0; ks < 4; ++ks) {
        int kg = (wave*4 + ks)*32 + q*8;          // bf16 k-index
        int ku = (wave*4 + ks)*16 + q*4;          // u32 k-index
        bf16x8 fa0 = *(const bf16x8*)&s_lds[rl*260 + ku];
        bf16x8 fa1 = *(const bf16x8*)&s_lds[(16 + rl)*260 + ku];
        bf16x8 fb  = *(const bf16x8*)&bp[kg];
        a0 = __builtin_amdgcn_mfma_f32_16x16x32_bf16(fa0, fb, a0, 0,0,0);
        a1 = __builtin_amdgcn_mfma_f32_16x16x32_bf16(fa1, fb, a1, 0,0,0);
      }
      #pragma unroll
      for (int reg = 0; reg < 4; ++reg) {
        RD[(wave*32 + (q*4 + reg))*16 + rl]      = a0[reg];
        RD[(wave*32 + (16 + q*4 + reg))*16 + rl] = a1[reg];
      }
      __syncthreads();
      for (int o = tx; o < 512; o += 256) {
        int bq = o >> 4, rlo = o & 15;
        float v = RD[bq*16 + rlo] + RD[(32 + bq)*16 + rlo]
                + RD[(64 + bq)*16 + rlo] + RD[(96 + bq)*16 + rlo];
        int nc = w*16 + rlo;
        if (nc < 512) __hip_atomic_store(&sva_g[bq*512 + nc], v, RLX, AG);
        else          __hip_atomic_store(&whh_g[bq*2048 + (nc - 512)], v, RLX, AG);
      }
    }
    gbar(bar, w, ph0, &s_dead);

    // ---- P2: scores[s][b] spread over all 256 WGs (4 wa_h rows per wave) ----
    {
      #pragma unroll
      for (int r = 0; r < 4; ++r) {
        int p = w*16 + wave*4 + r;      // row of wa_h = s*32 + b
        int b = p & 31, s = p >> 5;
        bf16x8 wv8 = *(const bf16x8*)&wa_h[(size_t)p*512 + lane*8];
        float sv[8];
        #pragma unroll
        for (int j = 0; j < 8; ++j)
          sv[j] = __hip_atomic_load(&sva_g[b*512 + lane*8 + j], RLX, AG);
        float acc;
        acc  = tanhf_(b2f((unsigned short)wv8[0]) + sv[0]) * ua0.x;
        acc += tanhf_(b2f((unsigned short)wv8[1]) + sv[1]) * ua0.y;
        acc += tanhf_(b2f((unsigned short)wv8[2]) + sv[2]) * ua0.z;
        acc += tanhf_(b2f((unsigned short)wv8[3]) + sv[3]) * ua0.w;
        acc += tanhf_(b2f((unsigned short)wv8[4]) + sv[4]) * ua1.x;
        acc += tanhf_(b2f((unsigned short)wv8[5]) + sv[5]) * ua1.y;
        acc += tanhf_(b2f((unsigned short)wv8[6]) + sv[6]) * ua1.z;
        acc += tanhf_(b2f((unsigned short)wv8[7]) + sv[7]) * ua1.w;
        #pragma unroll
        for (int o = 32; o > 0; o >>= 1) acc += __shfl_down(acc, o, 64);
        if (lane == 0)
          __hip_atomic_store(&scores_g[b*128 + s], acc * s_mask[s*32 + b], RLX, AG);
      }
    }
    gbar(bar, w, ph0 + 1u, &s_dead);

    // ---- P3: per-WG (b, chunk): softmax (redundant), gates+LSTM, ct ----
    {
      const int b = w >> 3, ch = w & 7;
      if (tx < 128)
        AL[tx] = __expf(__hip_atomic_load(&scores_g[b*128 + tx], RLX, AG));
      __syncthreads();
      if (tx < 64) {
        float sm = AL[tx] + AL[tx + 64];
        #pragma unroll
        for (int o = 32; o > 0; o >>= 1) sm += __shfl_down(sm, o, 64);
        if (tx == 0) GL[0] = rcpf_(sm);
      }
      __syncthreads();
      float inv = GL[0];
      __syncthreads();
      if (tx < 128) AL[tx] *= inv;
      __syncthreads();
      // gates partial: sum_s alpha[s] * G[s*32+b][n], n = ch*256 + cg*8 .. +8
      {
        const int cg = tx & 31, sg = tx >> 5;   // 8 s-groups of 16
        const int nn = ch*256 + cg*8;
        float a8[8] = {0.f,0.f,0.f,0.f,0.f,0.f,0.f,0.f};
        #pragma unroll
        for (int k = 0; k < 16; ++k) {
          int s = sg*16 + k;
          float av = AL[s];
          bf16x8 g8 = *(const bf16x8*)&G[((size_t)s*32 + b)*2048 + nn];
          a8[0] += av * b2f((unsigned short)g8[0]); a8[1] += av * b2f((unsigned short)g8[1]);
          a8[2] += av * b2f((unsigned short)g8[2]); a8[3] += av * b2f((unsigned short)g8[3]);
          a8[4] += av * b2f((unsigned short)g8[4]); a8[5] += av * b2f((unsigned short)g8[5]);
          a8[6] += av * b2f((unsigned short)g8[6]); a8[7] += av * b2f((unsigned short)g8[7]);
        }
        #pragma unroll
        for (int j = 0; j < 8; ++j) RD[(cg*8 + j)*8 + sg] = a8[j];
      }
      __syncthreads();
      {
        int n = ch*256 + tx;
        float sum = 0.f;
        #pragma unroll
        for (int k = 0; k < 8; ++k) sum += RD[tx*8 + k];
        GL[tx] = sum + __hip_atomic_load(&whh_g[b*2048 + n], RLX, AG) + bias_p[n];
      }
      __syncthreads();
      if (tx < 64) {
        float iv = GL[tx*4+0], fv = GL[tx*4+1], gv = GL[tx*4+2], ov = GL[tx*4+3];
        float co = c_sh[tx];
        float cn = sigf_(fv)*co + sigf_(iv)*tanhf_(gv);
        float sn = sigf_(ov)*tanhf_(cn);
        c_sh[tx] = cn;
        int h = ch*64 + tx;
        unsigned short hb = f2b(sn);
        Abf[((size_t)t*32 + b)*1536 + h] = hb;         // plain: consumed by k_gemm
        unsigned nb = (unsigned)__shfl_down((int)hb, 1, 64);
        if ((tx & 1) == 0) {
          unsigned pk = (unsigned)hb | (nb << 16);
          __hip_atomic_store(&s_bf[b*256 + (h >> 1)], pk, RLX, AG);
        }
      }
      // ct partial: sum_s alpha[s] * hs[s*32+b][jj], jj = ch*128 + cg2*8 .. +8
      {
        const int cg2 = tx & 15, sg2 = tx >> 4;  // 16 s-groups of 8
        const int jj = ch*128 + cg2*8;
        float c8[8] = {0.f,0.f,0.f,0.f,0.f,0.f,0.f,0.f};
        #pragma unroll
        for (int k = 0; k < 8; ++k) {
          int s = sg2*8 + k;
          float av = AL[s];
          bf16x8 h8 = *(const bf16x8*)&hs_b[((size_t)s*32 + b)*1024 + jj];
          c8[0] += av * b2f((unsigned short)h8[0]); c8[1] += av * b2f((unsigned short)h8[1]);
          c8[2] += av * b2f((unsigned short)h8[2]); c8[3] += av * b2f((unsigned short)h8[3]);
          c8[4] += av * b2f((unsigned short)h8[4]); c8[5] += av * b2f((unsigned short)h8[5]);
          c8[6] += av * b2f((unsigned short)h8[6]); c8[7] += av * b2f((unsigned short)h8[7]);
        }
        __syncthreads();
        #pragma unroll
        for (int j = 0; j < 8; ++j) RD[(cg2*8 + j)*16 + sg2] = c8[j];
      }
      __syncthreads();
      if (tx < 128) {
        float sum = 0.f;
        #pragma unroll
        for (int k = 0; k < 16; ++k) sum += RD[tx*16 + k];
        Abf[((size_t)t*32 + b)*1536 + 512 + ch*128 + tx] = f2b(sum);
      }
    }
    if (t < 63)
      gbar(bar, w, ph0 + 2u, &s_dead);
  }
}

// ---------------- loss + softmax normalize (unchanged) ----------------
__global__ __launch_bounds__(64) void k_loss(const float* __restrict__ L, const float* __restrict__ Z,
                                             const int* __restrict__ t_idx, const float* __restrict__ t_mask,
                                             float* __restrict__ out)
{
  const int b = blockIdx.x, t = threadIdx.x;
  const int row = t*32 + b;
  int id = t_idx[t*32 + b];
  float m = t_mask[t*32 + b];
  float l = L[(size_t)row*32000 + id];
  float v = (__logf(Z[row]) - l) * m;
  float vm = v, mm = m;
  for (int o = 32; o > 0; o >>= 1) { vm += __shfl_down(vm, o, 64); mm += __shfl_down(mm, o, 64); }
  if (t == 0) out[b] = vm / mm;
}

__global__ __launch_bounds__(256) void k_s2(float* __restrict__ L, const float* __restrict__ Z)
{
  const int row = blockIdx.x, tx = threadIdx.x;
  float* p = L + (size_t)row*32000;
  float rz = 1.f / Z[row];
  for (int n = tx; n < 32000; n += 256) p[n] = __expf(p[n]) * rz;
}

// ---------------- host ----------------
extern "C" void kernel_launch(void* const* d_in, const int* in_sizes, int n_in,
                              void* d_out, int out_size, void* d_ws, size_t ws_size,
                              hipStream_t stream)
{
  (void)in_sizes; (void)n_in; (void)out_size;
  const float* h_s    = (const float*)d_in[0];
  const float* s_mask = (const float*)d_in[1];
  const float* w_a    = (const float*)d_in[2];
  const float* v_a    = (const float*)d_in[3];
  const float* u_a    = (const float*)d_in[4];
  const float* w_b    = (const float*)d_in[5];
  const float* v_b    = (const float*)d_in[6];
  const float* W_ih   = (const float*)d_in[7];
  const float* W_hh   = (const float*)d_in[8];
  const float* b_ih   = (const float*)d_in[9];
  const float* b_hh   = (const float*)d_in[10];
  const float* t_mask = (const float*)d_in[11];
  const int*   t_idx  = (const int*)d_in[12];
  float* out = (float*)d_out;
  float* logits = out + 32;

  char* w = (char*)d_ws;
  size_t off = 0;
  auto take = [&](size_t bytes) -> void* {
    void* p = w + off; off += (bytes + 255) & ~(size_t)255; return p;
  };
  unsigned* bar          = (unsigned*)take(4096);
  float* sva_g           = (float*)take((size_t)32*512*4);
  float* whh_g           = (float*)take((size_t)32*2048*4);
  float* scores_g        = (float*)take((size_t)32*128*4);
  unsigned* s_bf         = (unsigned*)take((size_t)32*256*4);
  float* Z               = (float*)take((size_t)2048*4);
  float* bias_p          = (float*)take((size_t)2048*4);
  unsigned short* hs_b   = (unsigned short*)take((size_t)4096*1024*2);
  unsigned short* Wcomb  = (unsigned short*)take((size_t)2560*1024*2);
  unsigned short* Wv     = (unsigned short*)take((size_t)512*512*2);
  unsigned short* Whh_p  = (unsigned short*)take((size_t)2048*512*2);
  unsigned short* wa_hb  = (unsigned short*)take((size_t)4096*512*2);
  unsigned short* G      = (unsigned short*)take((size_t)4096*2048*2);
  unsigned short* Abf    = (unsigned short*)take((size_t)2048*1536*2);
  size_t base_need = off;
  bool useBt = (ws_size >= base_need + (size_t)32000*1536*2 + 256);
  unsigned short* Bt = useBt ? (unsigned short*)take((size_t)32000*1536*2) : nullptr;

  hipMemsetAsync(bar, 0, 4096, stream);
  hipMemsetAsync(s_bf, 0, (size_t)32*256*4, stream);   // s_0 = 0 (bf16 pairs of 0)
  hipMemsetAsync(Z, 0, 2048*4, stream);
  k_convert<<<4096, 256, 0, stream>>>(h_s, w_a, W_ih, v_a, W_hh, b_ih, b_hh,
                                      hs_b, Wcomb, Wv, Whh_p, bias_p);
  if (useBt)
    k_convB<<<dim3(24, 500), 256, 0, stream>>>(w_b, v_b, Bt);
  // [wa_h | G] = h_s @ [w_a | W_ih^T(perm)] : M=4096, N=2560, K=1024
  k_gemm<<<dim3(32,20), 256, 0, stream>>>(hs_b, nullptr, nullptr, 0, Wcomb, 1,
                                          wa_hb, G, 512, 512, 2048, 1, nullptr,
                                          4096, 2560, 1024);
  k_recur<<<256, 256, 0, stream>>>(wa_hb, G, hs_b, Wv, Whh_p, bias_p, s_mask, u_a,
                                   sva_g, whh_g, scores_g, s_bf, Abf, bar);
  // logits = [s_new|ct] @ [w_b; v_b] : M=2048, N=32000, K=1536 (+fused Z row-sums)
  if (useBt)
    k_gemm<<<dim3(16,250), 256, 0, stream>>>(Abf, nullptr, nullptr, 0, Bt, 1,
                                             logits, logits, 32000, 32000, 32000, 0, Z,
                                             2048, 32000, 1536);
  else
    k_gemm<<<dim3(16,250), 256, 0, stream>>>(Abf, w_b, v_b, 512, nullptr, 0,
                                             logits, logits, 32000, 32000, 32000, 0, Z,
                                             2048, 32000, 1536);
  k_loss<<<32, 64, 0, stream>>>(logits, Z, t_idx, t_mask, out);
  k_s2<<<2048, 256, 0, stream>>>(logits, Z);
}